// Round 13
// baseline (159.420 us; speedup 1.0000x reference)
//
#include <hip/hip_runtime.h>
#include <math.h>

#define LSEQ 8192
#define CCH  256
#define SDIM 64
#define PCHUNK 256            // chunks == blocks
#define CLEN 32               // steps per chunk
#define NBLK 256

// Software grid barrier: device-scope atomic counter, zeroed by a memset node
// in kernel_launch each call. All 256 blocks are co-resident (<=512 VGPR ->
// >=1 block/CU on 256 CUs), so spinning cannot deadlock.
__device__ __forceinline__ void gbar(unsigned* ctr) {
    __syncthreads();
    if (threadIdx.x == 0) {
        __threadfence();  // release this block's prior global writes
        __hip_atomic_fetch_add(ctr, 1u, __ATOMIC_RELEASE, __HIP_MEMORY_SCOPE_AGENT);
        while (__hip_atomic_load(ctr, __ATOMIC_ACQUIRE, __HIP_MEMORY_SCOPE_AGENT) < (unsigned)NBLK) {
            __builtin_amdgcn_s_sleep(1);
        }
        __threadfence();  // acquire other blocks' writes
    }
    __syncthreads();
}

// expm1(z) for |z| <= 4.1e-3 via 4-term series: rel err ~1e-12, fp32-exact.
__device__ __forceinline__ float expm1_small(float z) {
    return z * (1.0f + z * (0.5f + z * (0.16666667f + z * 0.041666668f)));
}

__global__ __launch_bounds__(256, 1) void s4d_one(
    const float* __restrict__ x,
    const float* __restrict__ lognegA,
    const float* __restrict__ Bm,
    const float* __restrict__ Cp,
    float* __restrict__ y,
    float* __restrict__ st,     // [SDIM][PCHUNK][CCH]
    unsigned* __restrict__ bars)
{
    const int lane = threadIdx.x & 63;
    const int wl   = threadIdx.x >> 6;      // wave 0..3
    const int b    = blockIdx.x;            // chunk
    const int c    = wl * 64 + lane;        // channel (phases B/D)
    const float dt = 6.25e-05f;

    // ---- x for this chunk: loaded once, lives in 32 VGPRs through phase D ----
    float xv[CLEN];
    {
        const float* xp = x + (size_t)(b * CLEN) * CCH + c;
#pragma unroll
        for (int i = 0; i < CLEN; ++i) xv[i] = xp[(size_t)i * CCH];
    }

    // ---- Phase B: local chunk scan (zero init), inline fp32 params ----
    {
        float rr[SDIM], h[SDIM];
        const float* lnaP = lognegA + c * SDIM;
#pragma unroll
        for (int s = 0; s < SDIM; ++s) {
            float A   = -expf(lnaP[s]);
            rr[s] = 1.0f + expm1_small(A * dt);   // r = exp(A*dt)
            h[s]  = 0.0f;
        }
#pragma unroll
        for (int i = 0; i < CLEN; ++i) {
            float xi = xv[i];
#pragma unroll
            for (int s = 0; s < SDIM; ++s)
                h[s] = fmaf(rr[s], h[s], xi);
        }
#pragma unroll
        for (int s = 0; s < SDIM; ++s)
            st[(size_t)(s * PCHUNK + b) * CCH + c] = h[s];
    }
    gbar(bars + 0);

    // ---- Phase C: chunk-carry scan, in place. block b -> (s2=b>>2, cb=b&3);
    //      wave wl owns p in [wl*64, wl*64+64). 2-level scan via LDS. ----
    {
        const int s2 = b >> 2;
        const int c2 = (b & 3) * 64 + lane;
        float A    = -expf(lognegA[c2 * SDIM + s2]);
        float adt  = A * dt;
        float rP   = expf(adt * 32.0f);     // r^CLEN
        float rP64 = expf(adt * 2048.0f);   // r^(CLEN*64)

        float e[64];
        size_t base = ((size_t)s2 * PCHUNK + wl * 64) * CCH + c2;
#pragma unroll
        for (int j = 0; j < 64; ++j) e[j] = st[base + (size_t)j * CCH];

        float agg = 0.0f;                   // segment aggregate (zero-init scan end)
#pragma unroll
        for (int j = 0; j < 64; ++j) agg = fmaf(rP, agg, e[j]);

        __shared__ float aggs[4][64];
        aggs[wl][lane] = agg;
        __syncthreads();

        float sin = 0.0f;                   // incoming state for this segment
#pragma unroll
        for (int v = 0; v < 3; ++v)
            if (v < wl) sin = fmaf(rP64, sin, aggs[v][lane]);

#pragma unroll
        for (int j = 0; j < 64; ++j) {
            st[base + (size_t)j * CCH] = sin;          // carry-in for chunk wl*64+j
            sin = fmaf(rP, sin, e[j]);
        }
    }
    gbar(bars + 1);

    // ---- Phase D: re-scan chunk with carry-in, emit y ----
    {
        float rr[SDIM], ww[SDIM], h[SDIM];
        const float* lnaP = lognegA + c * SDIM;
        const float* BP   = Bm + c * SDIM;
        const float* CpP  = Cp + c * SDIM;
#pragma unroll
        for (int s = 0; s < SDIM; ++s) {
            float A   = -expf(lnaP[s]);
            float em  = expm1_small(A * dt);
            rr[s] = 1.0f + em;
            ww[s] = CpP[s] * (em * BP[s] / A);         // Cp * (exp(A dt)-1) B / A
        }
#pragma unroll
        for (int s = 0; s < SDIM; ++s)
            h[s] = st[(size_t)(s * PCHUNK + b) * CCH + c];

        float* yp = y + (size_t)(b * CLEN) * CCH + c;
#pragma unroll
        for (int i = 0; i < CLEN; ++i) {
            float xi = xv[i];
            float a0 = 0.0f, a1 = 0.0f;
#pragma unroll
            for (int s = 0; s < SDIM; s += 2) {
                h[s]     = fmaf(rr[s],     h[s],     xi);
                a0       = fmaf(ww[s],     h[s],     a0);
                h[s + 1] = fmaf(rr[s + 1], h[s + 1], xi);
                a1       = fmaf(ww[s + 1], h[s + 1], a1);
            }
            yp[(size_t)i * CCH] = a0 + a1;
        }
    }
}

extern "C" void kernel_launch(void* const* d_in, const int* in_sizes, int n_in,
                              void* d_out, int out_size, void* d_ws, size_t ws_size,
                              hipStream_t stream) {
    const float* x       = (const float*)d_in[0];
    const float* lognegA = (const float*)d_in[1];
    const float* Bm      = (const float*)d_in[2];
    const float* Cp      = (const float*)d_in[3];
    float* out = (float*)d_out;

    unsigned* bars = (unsigned*)d_ws;
    float*    st   = (float*)d_ws + 64;     // 256B offset; st = 16.8 MB

    hipMemsetAsync(bars, 0, 256, stream);   // zero barrier counters every call
    s4d_one<<<dim3(NBLK), dim3(256), 0, stream>>>(x, lognegA, Bm, Cp, out, st, bars);
}

// Round 15
// 138.752 us; speedup vs baseline: 1.1490x; 1.1490x over previous
//
#include <hip/hip_runtime.h>
#include <math.h>

#define LSEQ 8192
#define CCH  256
#define SDIM 64
#define PCHUNK 256            // chunks == blocks
#define CLEN 32               // steps per chunk
#define NBLK 256

// Quiet software grid barrier. One agent release fence (buffer_wbl2) before
// the arrival add, RELAXED polls (no per-poll cache invalidate!), one agent
// acquire fence (buffer_inv) after exit. s_sleep(8) paces the poll loop.
// All 256 blocks co-resident (1 block/CU on 256 CUs) -> no deadlock.
__device__ __forceinline__ void gbar(unsigned* ctr) {
    __syncthreads();   // all waves' st-writes complete (vmcnt) before release
    if (threadIdx.x == 0) {
        __builtin_amdgcn_fence(__ATOMIC_RELEASE, "agent");   // wbl2: push L2
        __hip_atomic_fetch_add(ctr, 1u, __ATOMIC_RELAXED, __HIP_MEMORY_SCOPE_AGENT);
        while (__hip_atomic_load(ctr, __ATOMIC_RELAXED, __HIP_MEMORY_SCOPE_AGENT)
               < (unsigned)NBLK) {
            __builtin_amdgcn_s_sleep(8);                     // ~512 cyc/poll
        }
        __builtin_amdgcn_fence(__ATOMIC_ACQUIRE, "agent");   // inv: one time
    }
    __syncthreads();
}

// expm1(z) for |z| <= 4.1e-3 via 4-term series: rel err ~1e-12, fp32-exact.
__device__ __forceinline__ float expm1_small(float z) {
    return z * (1.0f + z * (0.5f + z * (0.16666667f + z * 0.041666668f)));
}

__global__ __launch_bounds__(256, 1) void s4d_one(
    const float* __restrict__ x,
    const float* __restrict__ lognegA,
    const float* __restrict__ Bm,
    const float* __restrict__ Cp,
    float* __restrict__ y,
    float* __restrict__ st,     // [SDIM][PCHUNK][CCH]
    unsigned* __restrict__ bars)
{
    const int lane = threadIdx.x & 63;
    const int wl   = threadIdx.x >> 6;      // wave 0..3
    const int b    = blockIdx.x;            // chunk
    const int c    = wl * 64 + lane;        // channel (phases B/D)
    const float dt = 6.25e-05f;

    // ---- x for this chunk: 32 VGPRs, reused in phase D ----
    float xv[CLEN];
    {
        const float* xp = x + (size_t)(b * CLEN) * CCH + c;
#pragma unroll
        for (int i = 0; i < CLEN; ++i) xv[i] = xp[(size_t)i * CCH];
    }

    // ---- Phase B: local chunk scan (zero init), inline fp32 params ----
    {
        float rr[SDIM], h[SDIM];
        const float* lnaP = lognegA + c * SDIM;
#pragma unroll
        for (int s = 0; s < SDIM; ++s) {
            float A = -expf(lnaP[s]);
            rr[s] = 1.0f + expm1_small(A * dt);   // r = exp(A*dt)
            h[s]  = 0.0f;
        }
#pragma unroll
        for (int i = 0; i < CLEN; ++i) {
            float xi = xv[i];
#pragma unroll
            for (int s = 0; s < SDIM; ++s)
                h[s] = fmaf(rr[s], h[s], xi);
        }
#pragma unroll
        for (int s = 0; s < SDIM; ++s)
            st[(size_t)(s * PCHUNK + b) * CCH + c] = h[s];
    }
    gbar(bars + 0);

    // ---- Phase C: chunk-carry scan, in place. block b -> (s2=b>>2, cb=b&3);
    //      wave wl owns p in [wl*64, wl*64+64). 2-level scan via LDS. ----
    {
        const int s2 = b >> 2;
        const int c2 = (b & 3) * 64 + lane;
        float A    = -expf(lognegA[c2 * SDIM + s2]);
        float adt  = A * dt;
        float rP   = expf(adt * 32.0f);     // r^CLEN
        float rP64 = expf(adt * 2048.0f);   // r^(CLEN*64)

        float e[64];
        size_t base = ((size_t)s2 * PCHUNK + wl * 64) * CCH + c2;
#pragma unroll
        for (int j = 0; j < 64; ++j) e[j] = st[base + (size_t)j * CCH];

        float agg = 0.0f;                   // segment aggregate
#pragma unroll
        for (int j = 0; j < 64; ++j) agg = fmaf(rP, agg, e[j]);

        __shared__ float aggs[4][64];
        aggs[wl][lane] = agg;
        __syncthreads();

        float sin = 0.0f;                   // incoming state for this segment
#pragma unroll
        for (int v = 0; v < 3; ++v)
            if (v < wl) sin = fmaf(rP64, sin, aggs[v][lane]);

#pragma unroll
        for (int j = 0; j < 64; ++j) {
            st[base + (size_t)j * CCH] = sin;   // carry-in for chunk wl*64+j
            sin = fmaf(rP, sin, e[j]);
        }
    }
    gbar(bars + 1);

    // ---- Phase D: re-scan with carry-in, two 32-state halves (spill-proof:
    //      peak live ~ rr32+ww32+h32+ya32+xv32 = 160 VGPR) ----
    {
        float ya[CLEN];
        const float* lnaP = lognegA + c * SDIM;
        const float* BP   = Bm + c * SDIM;
        const float* CpP  = Cp + c * SDIM;

#pragma unroll 1
        for (int half = 0; half < 2; ++half) {
            const int s0 = half * 32;
            float rr[32], ww[32], h[32];
#pragma unroll
            for (int s = 0; s < 32; ++s) {
                float A  = -expf(lnaP[s0 + s]);
                float em = expm1_small(A * dt);
                rr[s] = 1.0f + em;
                ww[s] = CpP[s0 + s] * (em * BP[s0 + s] / A);
            }
#pragma unroll
            for (int s = 0; s < 32; ++s)
                h[s] = st[(size_t)((s0 + s) * PCHUNK + b) * CCH + c];

#pragma unroll
            for (int i = 0; i < CLEN; ++i) {
                float xi = xv[i];
                float a0 = 0.0f, a1 = 0.0f;
#pragma unroll
                for (int s = 0; s < 32; s += 2) {
                    h[s]     = fmaf(rr[s],     h[s],     xi);
                    a0       = fmaf(ww[s],     h[s],     a0);
                    h[s + 1] = fmaf(rr[s + 1], h[s + 1], xi);
                    a1       = fmaf(ww[s + 1], h[s + 1], a1);
                }
                float part = a0 + a1;
                ya[i] = half ? (ya[i] + part) : part;
            }
        }

        float* yp = y + (size_t)(b * CLEN) * CCH + c;
#pragma unroll
        for (int i = 0; i < CLEN; ++i)
            yp[(size_t)i * CCH] = ya[i];
    }
}

extern "C" void kernel_launch(void* const* d_in, const int* in_sizes, int n_in,
                              void* d_out, int out_size, void* d_ws, size_t ws_size,
                              hipStream_t stream) {
    const float* x       = (const float*)d_in[0];
    const float* lognegA = (const float*)d_in[1];
    const float* Bm      = (const float*)d_in[2];
    const float* Cp      = (const float*)d_in[3];
    float* out = (float*)d_out;

    unsigned* bars = (unsigned*)d_ws;
    float*    st   = (float*)d_ws + 64;     // 256B offset; st = 16.8 MB

    hipMemsetAsync(bars, 0, 256, stream);   // zero barrier counters every call
    s4d_one<<<dim3(NBLK), dim3(256), 0, stream>>>(x, lognegA, Bm, Cp, out, st, bars);
}